// Round 14
// baseline (138.859 us; speedup 1.0000x reference)
//
#include <hip/hip_runtime.h>
#include <hip/hip_fp16.h>

// 3-layer GCN, input-dim aggregation (A(XW) = (AX)W), bucketed CSR build,
// fully fused layers, fp16 gather-source arrays (fp32 accumulate):
//   xs  [N,2]  fp16 -- layer1 gather     h1s [N,8] fp16 -- layer2 gather
//   h2s [N,32] fp16 -- layer3 gather
// R14: degree-sorted node permutation (built in p3 via 64-bin counting sort)
// removes the wave-straggler penalty in layers 1-2 (Poisson-degree max-of-64
// ~1.8x inflation). Layer3 keeps original order (pool needs batch-contiguity).

#define BSHIFT 9
#define BSZ 512
#define P2_TILE 2048
#define P1_BLOCKS 128
#define SRCMASK 0x1FFFF
#define NB3 32  // nodes per layer3 block

__device__ __forceinline__ unsigned fenc(float x) {
  unsigned b = __float_as_uint(x);
  return (b & 0x80000000u) ? ~b : (b | 0x80000000u);
}
__device__ __forceinline__ float fdec(unsigned k) {
  return (k & 0x80000000u) ? __uint_as_float(k ^ 0x80000000u)
                           : __uint_as_float(~k);
}
__device__ __forceinline__ unsigned pack2(float a, float b) {
  __half2 h = __floats2half2_rn(a, b);
  return *reinterpret_cast<unsigned*>(&h);
}
__device__ __forceinline__ float2 unpack2(unsigned u) {
  __half2 h = *reinterpret_cast<__half2*>(&u);
  return __half22float2(h);
}

// ---------------- CSR build ----------------

__global__ __launch_bounds__(256) void p1_hist_kernel(const int* __restrict__ dst,
                                                      int* __restrict__ hist2d, int E) {
  __shared__ int h[256];
  h[threadIdx.x] = 0;
  __syncthreads();
  for (int e = blockIdx.x * blockDim.x + threadIdx.x; e < E; e += gridDim.x * blockDim.x)
    atomicAdd(&h[dst[e] >> BSHIFT], 1);
  __syncthreads();
  hist2d[blockIdx.x * 256 + threadIdx.x] = h[threadIdx.x];
}

__global__ __launch_bounds__(256) void p1_scan_kernel(const int* __restrict__ hist2d,
                                                      int* __restrict__ bucketBase,
                                                      int* __restrict__ bucketCursor,
                                                      unsigned* __restrict__ pooled,
                                                      int B, int E, int G) {
  __shared__ int s[256];
  int t = threadIdx.x;
  int v = 0;
  for (int b = 0; b < P1_BLOCKS; ++b) v += hist2d[b * 256 + t];
  if (t >= B) v = 0;
  s[t] = v;
  __syncthreads();
  for (int o = 1; o < 256; o <<= 1) {
    int u = (t >= o) ? s[t - o] : 0;
    __syncthreads();
    s[t] += u;
    __syncthreads();
  }
  int excl = s[t] - v;
  bucketBase[t] = excl;
  bucketCursor[t] = excl;
  if (t == 0) bucketBase[256] = E;
  for (int i = t; i < G * 128; i += 256) pooled[i] = 0u;  // fenc key 0 < -inf
}

__global__ __launch_bounds__(256) void p2_partition_kernel(
    const int* __restrict__ src, const int* __restrict__ dst,
    int* __restrict__ bucketCursor, unsigned* __restrict__ part, int E) {
  __shared__ int hist[256];
  __shared__ int lbase[256];
  __shared__ int gbase[256];
  __shared__ int cur[256];
  __shared__ unsigned sbuf[P2_TILE];
  __shared__ unsigned abuf[P2_TILE];
  int t = threadIdx.x;
  int e0 = blockIdx.x * P2_TILE;
  int cnt = min(P2_TILE, E - e0);

  hist[t] = 0;
  __syncthreads();

  int myb[P2_TILE / 256];
  unsigned myp[P2_TILE / 256];
#pragma unroll
  for (int k = 0; k < P2_TILE / 256; ++k) {
    int i = t + k * 256;
    if (i < cnt) {
      int e = e0 + i;
      int d = dst[e];
      int b = d >> BSHIFT;
      myb[k] = b;
      myp[k] = ((unsigned)(d & (BSZ - 1)) << 17) | (unsigned)src[e];
      atomicAdd(&hist[b], 1);
    } else {
      myb[k] = -1;
      myp[k] = 0;
    }
  }
  __syncthreads();

  int v = hist[t];
  lbase[t] = v;
  __syncthreads();
  for (int o = 1; o < 256; o <<= 1) {
    int u = (t >= o) ? lbase[t - o] : 0;
    __syncthreads();
    lbase[t] += u;
    __syncthreads();
  }
  int excl = lbase[t] - v;
  __syncthreads();
  lbase[t] = excl;
  if (v > 0) gbase[t] = atomicAdd(&bucketCursor[t], v);
  cur[t] = 0;
  __syncthreads();

#pragma unroll
  for (int k = 0; k < P2_TILE / 256; ++k) {
    int b = myb[k];
    if (b >= 0) {
      int pos = atomicAdd(&cur[b], 1);
      int li = lbase[b] + pos;
      sbuf[li] = myp[k];
      abuf[li] = (unsigned)(gbase[b] + pos);
    }
  }
  __syncthreads();

#pragma unroll
  for (int k = 0; k < P2_TILE / 256; ++k) {
    int i = t + k * 256;
    if (i < cnt) part[abuf[i]] = sbuf[i];
  }
}

__global__ __launch_bounds__(512) void p3_build_kernel(
    const unsigned* __restrict__ part, const int* __restrict__ bucketBase,
    const float* __restrict__ x, unsigned* __restrict__ xsh,
    float* __restrict__ dis, int* __restrict__ rp, unsigned* __restrict__ csr,
    int* __restrict__ perm, int N, int B, int E) {
  __shared__ int hist[BSZ];
  __shared__ int scn[BSZ];
  __shared__ int dh[64];
  __shared__ int dc[64];
  int b = blockIdx.x, t = threadIdx.x;
  int base = bucketBase[b], end = bucketBase[b + 1];
  int cnt = end - base;

  hist[t] = 0;
  __syncthreads();
  for (int i = t; i < cnt; i += BSZ) atomicAdd(&hist[part[base + i] >> 17], 1);
  __syncthreads();

  int v = hist[t];
  scn[t] = v;
  __syncthreads();
  for (int o = 1; o < BSZ; o <<= 1) {
    int u = (t >= o) ? scn[t - o] : 0;
    __syncthreads();
    scn[t] += u;
    __syncthreads();
  }
  int excl = scn[t] - v;

  int n = (b << BSHIFT) + t;
  if (n < N) {
    float dn = rsqrtf((float)v + 1.0f);
    dis[n] = dn;
    rp[n] = base + excl;
    float2 xn = *reinterpret_cast<const float2*>(x + 2 * (size_t)n);
    xsh[n] = pack2(dn * xn.x, dn * xn.y);  // fp16 pre-scaled x
  }
  if (b == B - 1 && t == 0) rp[N] = E;

  hist[t] = excl;  // reuse as csr cursor
  if (t < 64) dh[t] = 0;
  __syncthreads();
  for (int i = t; i < cnt; i += BSZ) {
    unsigned p = part[base + i];
    int pos = atomicAdd(&hist[p >> 17], 1);
    csr[base + pos] = p & SRCMASK;
  }

  // degree-sorted permutation within the bucket (64-bin counting sort)
  int bin = min(v, 63);
  if (n < N) atomicAdd(&dh[bin], 1);
  __syncthreads();
  if (t == 0) {
    int run = 0;
#pragma unroll
    for (int i = 0; i < 64; ++i) {
      dc[i] = run;
      run += dh[i];
    }
  }
  __syncthreads();
  if (n < N) {
    int pos = atomicAdd(&dc[bin], 1);
    perm[(b << BSHIFT) + pos] = n;
  }
}

// ---------------- fused layers ----------------

// layer1: thread-per-PERMUTED-node; gathers fp16 xs; writes fp16 h1s.
__global__ __launch_bounds__(256) void layer1_kernel(
    const int* __restrict__ rp, const unsigned* __restrict__ csr, const float* __restrict__ dis,
    const int* __restrict__ perm,
    const unsigned* __restrict__ xsh, const float* __restrict__ W1, const float* __restrict__ b1,
    uint4* __restrict__ h1h, int N) {
  __shared__ float sW[16];
  __shared__ float sb[8];
  int t = threadIdx.x;
  if (t < 16) sW[t] = W1[t];
  if (t < 8) sb[t] = b1[t];
  __syncthreads();
  int tid = blockIdx.x * blockDim.x + t;
  if (tid >= N) return;
  int n = perm[tid];
  float2 a = unpack2(xsh[n]);  // self
  int j0 = rp[n], j1 = rp[n + 1];
#pragma unroll 4
  for (int j = j0; j < j1; ++j) {
    const float2 v = unpack2(xsh[csr[j]]);
    a.x += v.x;
    a.y += v.y;
  }
  float dn = dis[n];
  float ax = dn * a.x, ay = dn * a.y;
  uint4 pk;
  unsigned* pw = &pk.x;
#pragma unroll
  for (int fc = 0; fc < 4; ++fc) {
    float e0 = dn * fmaxf(ax * sW[fc * 2 + 0] + ay * sW[8 + fc * 2 + 0] + sb[fc * 2 + 0], 0.f);
    float e1 = dn * fmaxf(ax * sW[fc * 2 + 1] + ay * sW[8 + fc * 2 + 1] + sb[fc * 2 + 1], 0.f);
    pw[fc] = pack2(e0, e1);
  }
  h1h[n] = pk;
}

// layer2: thread-per-PERMUTED-node; gathers fp16 h1s; writes fp16 h2s.
__global__ __launch_bounds__(256) void layer2_kernel(
    const int* __restrict__ rp, const unsigned* __restrict__ csr, const float* __restrict__ dis,
    const int* __restrict__ perm,
    const uint4* __restrict__ h1h, const float* __restrict__ W2, const float* __restrict__ b2,
    __half* __restrict__ h2h, int N) {
  __shared__ float sW[256];  // [8][32]
  __shared__ float sb[32];
  int t = threadIdx.x;
  sW[t] = W2[t];
  if (t < 32) sb[t] = b2[t];
  __syncthreads();
  int tid = blockIdx.x * blockDim.x + t;
  if (tid >= N) return;
  int n = perm[tid];
  float acc[8];
  {
    uint4 sv = h1h[n];
    float2 f0 = unpack2(sv.x), f1 = unpack2(sv.y), f2 = unpack2(sv.z), f3 = unpack2(sv.w);
    acc[0] = f0.x; acc[1] = f0.y; acc[2] = f1.x; acc[3] = f1.y;
    acc[4] = f2.x; acc[5] = f2.y; acc[6] = f3.x; acc[7] = f3.y;
  }
  int j0 = rp[n], j1 = rp[n + 1];
#pragma unroll 4
  for (int j = j0; j < j1; ++j) {
    uint4 v = h1h[csr[j]];
    float2 g0 = unpack2(v.x), g1 = unpack2(v.y), g2 = unpack2(v.z), g3 = unpack2(v.w);
    acc[0] += g0.x; acc[1] += g0.y; acc[2] += g1.x; acc[3] += g1.y;
    acc[4] += g2.x; acc[5] += g2.y; acc[6] += g3.x; acc[7] += g3.y;
  }
  float dn = dis[n];
#pragma unroll
  for (int k = 0; k < 8; ++k) acc[k] *= dn;
  uint4 pk[4];  // 16 unsigneds = 32 halves = full row
  unsigned* pw = &pk[0].x;
#pragma unroll
  for (int fc = 0; fc < 8; ++fc) {
    float4 o;
    o.x = sb[fc * 4 + 0]; o.y = sb[fc * 4 + 1]; o.z = sb[fc * 4 + 2]; o.w = sb[fc * 4 + 3];
#pragma unroll
    for (int k = 0; k < 8; ++k) {
      const float4 w = *reinterpret_cast<const float4*>(&sW[k * 32 + fc * 4]);
      float a = acc[k];
      o.x += a * w.x; o.y += a * w.y; o.z += a * w.z; o.w += a * w.w;
    }
    o.x = dn * fmaxf(o.x, 0.f);
    o.y = dn * fmaxf(o.y, 0.f);
    o.z = dn * fmaxf(o.z, 0.f);
    o.w = dn * fmaxf(o.w, 0.f);
    pw[fc * 2 + 0] = pack2(o.x, o.y);
    pw[fc * 2 + 1] = pack2(o.z, o.w);
  }
  uint4* dst16 = reinterpret_cast<uint4*>(h2h + (size_t)n * 32);
  dst16[0] = pk[0];
  dst16[1] = pk[1];
  dst16[2] = pk[2];
  dst16[3] = pk[3];
}

// layer3 fused: 32 nodes per 128-thread block (ORIGINAL order), 4 threads/node,
// per-node register accumulation over fp16 h2s, then matvec + segmented max-pool.
__global__ __launch_bounds__(128) void layer3_pool_kernel(
    const int* __restrict__ rp, const unsigned* __restrict__ csr, const float* __restrict__ dis,
    const __half* __restrict__ h2h, const float* __restrict__ W3, const float* __restrict__ b3,
    const int* __restrict__ batch, unsigned* __restrict__ pooled, int N) {
  __shared__ float rows[NB3][32];
  __shared__ float dnv[NB3];
  int t = threadIdx.x;
  int gi = t >> 2;          // node slot 0..31
  int q = t & 3;            // feature quarter (8 features)

  int n0 = blockIdx.x * NB3;
  int m = min(NB3, N - n0);

  if (t < m) dnv[t] = dis[n0 + t];

  if (gi < m) {
    int n = n0 + gi;
    uint4 sv = *reinterpret_cast<const uint4*>(h2h + (size_t)n * 32 + q * 8);
    float2 f0 = unpack2(sv.x), f1 = unpack2(sv.y), f2 = unpack2(sv.z), f3 = unpack2(sv.w);
    float acc[8] = {f0.x, f0.y, f1.x, f1.y, f2.x, f2.y, f3.x, f3.y};
    int j0 = rp[n], j1 = rp[n + 1];
#pragma unroll 4
    for (int j = j0; j < j1; ++j) {
      int s = csr[j];
      uint4 v = *reinterpret_cast<const uint4*>(h2h + (size_t)s * 32 + q * 8);
      float2 g0 = unpack2(v.x), g1 = unpack2(v.y), g2 = unpack2(v.z), g3 = unpack2(v.w);
      acc[0] += g0.x; acc[1] += g0.y; acc[2] += g1.x; acc[3] += g1.y;
      acc[4] += g2.x; acc[5] += g2.y; acc[6] += g3.x; acc[7] += g3.y;
    }
#pragma unroll
    for (int i = 0; i < 8; ++i) rows[gi][q * 8 + i] = acc[i];
  }
  __syncthreads();

  // matvec + segmented max: thread t owns output feature t (128 threads)
  float Wreg[32];
#pragma unroll
  for (int k = 0; k < 32; ++k) Wreg[k] = W3[k * 128 + t];
  float bb = b3[t];

  int curg = batch[n0];
  float runmax = -INFINITY;
  for (int r = 0; r < m; ++r) {
    int g = batch[n0 + r];
    if (g != curg) {
      atomicMax(&pooled[(size_t)curg * 128 + t], fenc(runmax));
      runmax = -INFINITY;
      curg = g;
    }
    float acc = 0.f;
#pragma unroll
    for (int k = 0; k < 32; ++k) acc += rows[r][k] * Wreg[k];
    runmax = fmaxf(runmax, dnv[r] * acc + bb);
  }
  atomicMax(&pooled[(size_t)curg * 128 + t], fenc(runmax));
}

__global__ __launch_bounds__(128) void head_kernel(
    const unsigned* __restrict__ pooled, const float* __restrict__ Wl,
    const float* __restrict__ bl, float* __restrict__ out, int G) {
  int g = blockIdx.x;
  int t = threadIdx.x;  // 128
  float p = fdec(pooled[(size_t)g * 128 + t]);
  __shared__ float red[128];
  __shared__ float sj[3];
  for (int j = 0; j < 3; ++j) {
    red[t] = p * Wl[t * 3 + j];
    __syncthreads();
    for (int k = 64; k > 0; k >>= 1) {
      if (t < k) red[t] += red[t + k];
      __syncthreads();
    }
    if (t == 0) sj[j] = red[0];
    __syncthreads();
  }
  if (t == 0) {
    float l0 = sj[0] + bl[0], l1 = sj[1] + bl[1], l2 = sj[2] + bl[2];
    float m = fmaxf(l0, fmaxf(l1, l2));
    float lse = logf(expf(l0 - m) + expf(l1 - m) + expf(l2 - m));
    out[g * 3 + 0] = l0 - m - lse;
    out[g * 3 + 1] = l1 - m - lse;
    out[g * 3 + 2] = l2 - m - lse;
  }
}

extern "C" void kernel_launch(void* const* d_in, const int* in_sizes, int n_in,
                              void* d_out, int out_size, void* d_ws, size_t ws_size,
                              hipStream_t stream) {
  const float* x = (const float*)d_in[0];
  const int* ei = (const int*)d_in[1];
  const int* batch = (const int*)d_in[2];
  const float* W1 = (const float*)d_in[3];
  const float* b1 = (const float*)d_in[4];
  const float* W2 = (const float*)d_in[5];
  const float* b2 = (const float*)d_in[6];
  const float* W3 = (const float*)d_in[7];
  const float* b3 = (const float*)d_in[8];
  const float* Wl = (const float*)d_in[9];
  const float* bl = (const float*)d_in[10];
  float* out = (float*)d_out;

  const int N = in_sizes[0] / 2;  // x [N,2]
  const int E = in_sizes[1] / 2;  // edge_index [2,E]
  const int G = out_size / 3;     // logits [G,3]

  const int* src = ei;
  const int* dstp = ei + E;

  const int B = (N + BSZ - 1) / BSZ;  // <=256 for N<=131072

  size_t NP = ((size_t)N + 256) & ~(size_t)255;
  size_t EP = ((size_t)E + 255) & ~(size_t)255;

  float* dis = (float*)d_ws;                 // NP
  int* rp = (int*)d_ws + NP;                 // NP
  unsigned* csr = (unsigned*)(rp + NP);      // EP
  unsigned* part = (unsigned*)(csr + EP);    // EP
  int* bucketBase = (int*)(part + EP);       // 512
  int* bucketCursor = bucketBase + 512;      // 512
  int* hist2d = bucketCursor + 512;          // P1_BLOCKS*256
  int* perm = hist2d + P1_BLOCKS * 256;      // NP
  float* arena = (float*)(perm + NP);

  unsigned* xsh = (unsigned*)arena;                         // N uints  (fp16 x2)
  uint4* h1h = (uint4*)(arena + (size_t)N);                 // N uint4  (fp16 x8)
  __half* h2h = (__half*)(arena + (size_t)5 * N);           // N*32 fp16
  unsigned* pooled = (unsigned*)(arena + (size_t)21 * N);   // G*128

  const int BS = 256;
  auto cdiv = [](long long a, long long b) { return (int)((a + b - 1) / b); };

  // ---- CSR build
  p1_hist_kernel<<<P1_BLOCKS, 256, 0, stream>>>(dstp, hist2d, E);
  p1_scan_kernel<<<1, 256, 0, stream>>>(hist2d, bucketBase, bucketCursor, pooled, B, E, G);
  p2_partition_kernel<<<cdiv(E, P2_TILE), 256, 0, stream>>>(src, dstp, bucketCursor, part, E);
  p3_build_kernel<<<B, BSZ, 0, stream>>>(part, bucketBase, x, xsh, dis, rp, csr, perm, N, B, E);

  // ---- fused layers
  layer1_kernel<<<cdiv(N, BS), BS, 0, stream>>>(rp, csr, dis, perm, xsh, W1, b1, h1h, N);
  layer2_kernel<<<cdiv(N, BS), BS, 0, stream>>>(rp, csr, dis, perm, h1h, W2, b2, h2h, N);
  layer3_pool_kernel<<<cdiv(N, NB3), 128, 0, stream>>>(rp, csr, dis, h2h, W3, b3, batch, pooled, N);

  // ---- head
  head_kernel<<<G, 128, 0, stream>>>(pooled, Wl, bl, out, G);
}

// Round 15
// 118.995 us; speedup vs baseline: 1.1669x; 1.1669x over previous
//
#include <hip/hip_runtime.h>
#include <hip/hip_fp16.h>

// 3-layer GCN, input-dim aggregation (A(XW) = (AX)W), bucketed CSR build,
// fully fused layers, fp16 gather-source arrays (fp32 accumulate):
//   xs  [N,2]  fp16 -- layer1 gather     h1s [N,8] fp16 -- layer2 gather
//   h2s [N,32] fp16 -- layer3 gather
// R15: CSR build without the separate histogram pass -- p2 writes into
// fixed-capacity per-bucket regions (CAP=16384 >> mean 8.2K, sd 90),
// reserving space via one global atomicAdd per (block,bucket); a 1-block
// scan of the final counts gives compact bases for p3. One fewer full
// edge pass + one fewer launch vs R13. (R14's degree-perm reverted: it
// cost more in scattered writes than it saved in stragglers.)

#define BSHIFT 9
#define BSZ 512
#define P2_TILE 2048
#define CAP 16384
#define SRCMASK 0x1FFFF
#define NB3 32  // nodes per layer3 block

__device__ __forceinline__ unsigned fenc(float x) {
  unsigned b = __float_as_uint(x);
  return (b & 0x80000000u) ? ~b : (b | 0x80000000u);
}
__device__ __forceinline__ float fdec(unsigned k) {
  return (k & 0x80000000u) ? __uint_as_float(k ^ 0x80000000u)
                           : __uint_as_float(~k);
}
__device__ __forceinline__ unsigned pack2(float a, float b) {
  __half2 h = __floats2half2_rn(a, b);
  return *reinterpret_cast<unsigned*>(&h);
}
__device__ __forceinline__ float2 unpack2(unsigned u) {
  __half2 h = *reinterpret_cast<__half2*>(&u);
  return __half22float2(h);
}

// ---------------- CSR build ----------------

// partition edges into fixed-capacity bucket regions; LDS-reordered so
// global writes are run-coalesced. bucketCount doubles as region cursor.
__global__ __launch_bounds__(256) void p2_partition_kernel(
    const int* __restrict__ src, const int* __restrict__ dst,
    int* __restrict__ bucketCount, unsigned* __restrict__ part, int E) {
  __shared__ int hist[256];
  __shared__ int lbase[256];
  __shared__ int gbase[256];
  __shared__ int cur[256];
  __shared__ unsigned sbuf[P2_TILE];
  __shared__ unsigned abuf[P2_TILE];
  int t = threadIdx.x;
  int e0 = blockIdx.x * P2_TILE;
  int cnt = min(P2_TILE, E - e0);

  hist[t] = 0;
  __syncthreads();

  int myb[P2_TILE / 256];
  unsigned myp[P2_TILE / 256];
#pragma unroll
  for (int k = 0; k < P2_TILE / 256; ++k) {
    int i = t + k * 256;
    if (i < cnt) {
      int e = e0 + i;
      int d = dst[e];
      int b = d >> BSHIFT;
      myb[k] = b;
      myp[k] = ((unsigned)(d & (BSZ - 1)) << 17) | (unsigned)src[e];
      atomicAdd(&hist[b], 1);
    } else {
      myb[k] = -1;
      myp[k] = 0;
    }
  }
  __syncthreads();

  int v = hist[t];
  lbase[t] = v;
  __syncthreads();
  for (int o = 1; o < 256; o <<= 1) {
    int u = (t >= o) ? lbase[t - o] : 0;
    __syncthreads();
    lbase[t] += u;
    __syncthreads();
  }
  int excl = lbase[t] - v;
  __syncthreads();
  lbase[t] = excl;
  if (v > 0) gbase[t] = atomicAdd(&bucketCount[t], v);  // region reservation
  cur[t] = 0;
  __syncthreads();

#pragma unroll
  for (int k = 0; k < P2_TILE / 256; ++k) {
    int b = myb[k];
    if (b >= 0) {
      int pos = atomicAdd(&cur[b], 1);
      int li = lbase[b] + pos;
      sbuf[li] = myp[k];
      abuf[li] = (unsigned)(b * CAP + gbase[b] + pos);
    }
  }
  __syncthreads();

#pragma unroll
  for (int k = 0; k < P2_TILE / 256; ++k) {
    int i = t + k * 256;
    if (i < cnt) part[abuf[i]] = sbuf[i];
  }
}

// 1-block exclusive scan of final bucket counts -> compact csr bases.
__global__ __launch_bounds__(256) void scan_kernel(const int* __restrict__ bucketCount,
                                                   int* __restrict__ bucketBase, int B) {
  __shared__ int s[256];
  int t = threadIdx.x;
  int v = (t < B) ? bucketCount[t] : 0;
  s[t] = v;
  __syncthreads();
  for (int o = 1; o < 256; o <<= 1) {
    int u = (t >= o) ? s[t - o] : 0;
    __syncthreads();
    s[t] += u;
    __syncthreads();
  }
  bucketBase[t] = s[t] - v;
}

// per-bucket: local deg hist -> dis, rp, fp16-prescaled x; scatter region->csr.
__global__ __launch_bounds__(512) void p3_build_kernel(
    const unsigned* __restrict__ part, const int* __restrict__ bucketCount,
    const int* __restrict__ bucketBase,
    const float* __restrict__ x, unsigned* __restrict__ xsh,
    float* __restrict__ dis, int* __restrict__ rp, unsigned* __restrict__ csr,
    int N, int B, int E) {
  __shared__ int hist[BSZ];
  __shared__ int scn[BSZ];
  int b = blockIdx.x, t = threadIdx.x;
  const unsigned* reg = part + (size_t)b * CAP;
  int cnt = bucketCount[b];
  int wbase = bucketBase[b];

  hist[t] = 0;
  __syncthreads();
  for (int i = t; i < cnt; i += BSZ) atomicAdd(&hist[reg[i] >> 17], 1);
  __syncthreads();

  int v = hist[t];
  scn[t] = v;
  __syncthreads();
  for (int o = 1; o < BSZ; o <<= 1) {
    int u = (t >= o) ? scn[t - o] : 0;
    __syncthreads();
    scn[t] += u;
    __syncthreads();
  }
  int excl = scn[t] - v;

  int n = (b << BSHIFT) + t;
  if (n < N) {
    float dn = rsqrtf((float)v + 1.0f);
    dis[n] = dn;
    rp[n] = wbase + excl;
    float2 xn = *reinterpret_cast<const float2*>(x + 2 * (size_t)n);
    xsh[n] = pack2(dn * xn.x, dn * xn.y);  // fp16 pre-scaled x
  }
  if (b == B - 1 && t == 0) rp[N] = E;

  hist[t] = excl;  // reuse as cursor
  __syncthreads();
  for (int i = t; i < cnt; i += BSZ) {
    unsigned p = reg[i];
    int pos = atomicAdd(&hist[p >> 17], 1);
    csr[wbase + pos] = p & SRCMASK;
  }
}

// ---------------- fused layers ----------------

// layer1: thread-per-node; gathers fp16 xs (4B/edge); writes fp16 h1s (16B).
__global__ __launch_bounds__(256) void layer1_kernel(
    const int* __restrict__ rp, const unsigned* __restrict__ csr, const float* __restrict__ dis,
    const unsigned* __restrict__ xsh, const float* __restrict__ W1, const float* __restrict__ b1,
    uint4* __restrict__ h1h, int N) {
  __shared__ float sW[16];
  __shared__ float sb[8];
  int t = threadIdx.x;
  if (t < 16) sW[t] = W1[t];
  if (t < 8) sb[t] = b1[t];
  __syncthreads();
  int n = blockIdx.x * blockDim.x + t;
  if (n >= N) return;
  float2 a = unpack2(xsh[n]);  // self
  int j0 = rp[n], j1 = rp[n + 1];
#pragma unroll 4
  for (int j = j0; j < j1; ++j) {
    const float2 v = unpack2(xsh[csr[j]]);
    a.x += v.x;
    a.y += v.y;
  }
  float dn = dis[n];
  float ax = dn * a.x, ay = dn * a.y;
  uint4 pk;
  unsigned* pw = &pk.x;
#pragma unroll
  for (int fc = 0; fc < 4; ++fc) {
    float e0 = dn * fmaxf(ax * sW[fc * 2 + 0] + ay * sW[8 + fc * 2 + 0] + sb[fc * 2 + 0], 0.f);
    float e1 = dn * fmaxf(ax * sW[fc * 2 + 1] + ay * sW[8 + fc * 2 + 1] + sb[fc * 2 + 1], 0.f);
    pw[fc] = pack2(e0, e1);
  }
  h1h[n] = pk;
}

// layer2: thread-per-node; gathers fp16 h1s (one uint4/edge); writes fp16 h2s.
__global__ __launch_bounds__(256) void layer2_kernel(
    const int* __restrict__ rp, const unsigned* __restrict__ csr, const float* __restrict__ dis,
    const uint4* __restrict__ h1h, const float* __restrict__ W2, const float* __restrict__ b2,
    __half* __restrict__ h2h, int N) {
  __shared__ float sW[256];  // [8][32]
  __shared__ float sb[32];
  int t = threadIdx.x;
  sW[t] = W2[t];
  if (t < 32) sb[t] = b2[t];
  __syncthreads();
  int n = blockIdx.x * blockDim.x + t;
  if (n >= N) return;
  float acc[8];
  {
    uint4 sv = h1h[n];
    float2 f0 = unpack2(sv.x), f1 = unpack2(sv.y), f2 = unpack2(sv.z), f3 = unpack2(sv.w);
    acc[0] = f0.x; acc[1] = f0.y; acc[2] = f1.x; acc[3] = f1.y;
    acc[4] = f2.x; acc[5] = f2.y; acc[6] = f3.x; acc[7] = f3.y;
  }
  int j0 = rp[n], j1 = rp[n + 1];
#pragma unroll 4
  for (int j = j0; j < j1; ++j) {
    uint4 v = h1h[csr[j]];
    float2 g0 = unpack2(v.x), g1 = unpack2(v.y), g2 = unpack2(v.z), g3 = unpack2(v.w);
    acc[0] += g0.x; acc[1] += g0.y; acc[2] += g1.x; acc[3] += g1.y;
    acc[4] += g2.x; acc[5] += g2.y; acc[6] += g3.x; acc[7] += g3.y;
  }
  float dn = dis[n];
#pragma unroll
  for (int k = 0; k < 8; ++k) acc[k] *= dn;
  uint4 pk[4];  // 16 unsigneds = 32 halves = full row
  unsigned* pw = &pk[0].x;
#pragma unroll
  for (int fc = 0; fc < 8; ++fc) {
    float4 o;
    o.x = sb[fc * 4 + 0]; o.y = sb[fc * 4 + 1]; o.z = sb[fc * 4 + 2]; o.w = sb[fc * 4 + 3];
#pragma unroll
    for (int k = 0; k < 8; ++k) {
      const float4 w = *reinterpret_cast<const float4*>(&sW[k * 32 + fc * 4]);
      float a = acc[k];
      o.x += a * w.x; o.y += a * w.y; o.z += a * w.z; o.w += a * w.w;
    }
    o.x = dn * fmaxf(o.x, 0.f);
    o.y = dn * fmaxf(o.y, 0.f);
    o.z = dn * fmaxf(o.z, 0.f);
    o.w = dn * fmaxf(o.w, 0.f);
    pw[fc * 2 + 0] = pack2(o.x, o.y);
    pw[fc * 2 + 1] = pack2(o.z, o.w);
  }
  uint4* dst16 = reinterpret_cast<uint4*>(h2h + (size_t)n * 32);
  dst16[0] = pk[0];
  dst16[1] = pk[1];
  dst16[2] = pk[2];
  dst16[3] = pk[3];
}

// layer3 fused: 32 nodes per 128-thread block, 4 threads/node, per-node
// register accumulation over fp16 h2s, then matvec + segmented max-pool.
__global__ __launch_bounds__(128) void layer3_pool_kernel(
    const int* __restrict__ rp, const unsigned* __restrict__ csr, const float* __restrict__ dis,
    const __half* __restrict__ h2h, const float* __restrict__ W3, const float* __restrict__ b3,
    const int* __restrict__ batch, unsigned* __restrict__ pooled, int N) {
  __shared__ float rows[NB3][32];
  __shared__ float dnv[NB3];
  int t = threadIdx.x;
  int gi = t >> 2;          // node slot 0..31
  int q = t & 3;            // feature quarter (8 features)

  int n0 = blockIdx.x * NB3;
  int m = min(NB3, N - n0);

  if (t < m) dnv[t] = dis[n0 + t];

  if (gi < m) {
    int n = n0 + gi;
    uint4 sv = *reinterpret_cast<const uint4*>(h2h + (size_t)n * 32 + q * 8);
    float2 f0 = unpack2(sv.x), f1 = unpack2(sv.y), f2 = unpack2(sv.z), f3 = unpack2(sv.w);
    float acc[8] = {f0.x, f0.y, f1.x, f1.y, f2.x, f2.y, f3.x, f3.y};
    int j0 = rp[n], j1 = rp[n + 1];
#pragma unroll 4
    for (int j = j0; j < j1; ++j) {
      int s = csr[j];
      uint4 v = *reinterpret_cast<const uint4*>(h2h + (size_t)s * 32 + q * 8);
      float2 g0 = unpack2(v.x), g1 = unpack2(v.y), g2 = unpack2(v.z), g3 = unpack2(v.w);
      acc[0] += g0.x; acc[1] += g0.y; acc[2] += g1.x; acc[3] += g1.y;
      acc[4] += g2.x; acc[5] += g2.y; acc[6] += g3.x; acc[7] += g3.y;
    }
#pragma unroll
    for (int i = 0; i < 8; ++i) rows[gi][q * 8 + i] = acc[i];
  }
  __syncthreads();

  // matvec + segmented max: thread t owns output feature t (128 threads)
  float Wreg[32];
#pragma unroll
  for (int k = 0; k < 32; ++k) Wreg[k] = W3[k * 128 + t];
  float bb = b3[t];

  int curg = batch[n0];
  float runmax = -INFINITY;
  for (int r = 0; r < m; ++r) {
    int g = batch[n0 + r];
    if (g != curg) {
      atomicMax(&pooled[(size_t)curg * 128 + t], fenc(runmax));
      runmax = -INFINITY;
      curg = g;
    }
    float acc = 0.f;
#pragma unroll
    for (int k = 0; k < 32; ++k) acc += rows[r][k] * Wreg[k];
    runmax = fmaxf(runmax, dnv[r] * acc + bb);
  }
  atomicMax(&pooled[(size_t)curg * 128 + t], fenc(runmax));
}

__global__ __launch_bounds__(128) void head_kernel(
    const unsigned* __restrict__ pooled, const float* __restrict__ Wl,
    const float* __restrict__ bl, float* __restrict__ out, int G) {
  int g = blockIdx.x;
  int t = threadIdx.x;  // 128
  float p = fdec(pooled[(size_t)g * 128 + t]);
  __shared__ float red[128];
  __shared__ float sj[3];
  for (int j = 0; j < 3; ++j) {
    red[t] = p * Wl[t * 3 + j];
    __syncthreads();
    for (int k = 64; k > 0; k >>= 1) {
      if (t < k) red[t] += red[t + k];
      __syncthreads();
    }
    if (t == 0) sj[j] = red[0];
    __syncthreads();
  }
  if (t == 0) {
    float l0 = sj[0] + bl[0], l1 = sj[1] + bl[1], l2 = sj[2] + bl[2];
    float m = fmaxf(l0, fmaxf(l1, l2));
    float lse = logf(expf(l0 - m) + expf(l1 - m) + expf(l2 - m));
    out[g * 3 + 0] = l0 - m - lse;
    out[g * 3 + 1] = l1 - m - lse;
    out[g * 3 + 2] = l2 - m - lse;
  }
}

extern "C" void kernel_launch(void* const* d_in, const int* in_sizes, int n_in,
                              void* d_out, int out_size, void* d_ws, size_t ws_size,
                              hipStream_t stream) {
  const float* x = (const float*)d_in[0];
  const int* ei = (const int*)d_in[1];
  const int* batch = (const int*)d_in[2];
  const float* W1 = (const float*)d_in[3];
  const float* b1 = (const float*)d_in[4];
  const float* W2 = (const float*)d_in[5];
  const float* b2 = (const float*)d_in[6];
  const float* W3 = (const float*)d_in[7];
  const float* b3 = (const float*)d_in[8];
  const float* Wl = (const float*)d_in[9];
  const float* bl = (const float*)d_in[10];
  float* out = (float*)d_out;

  const int N = in_sizes[0] / 2;  // x [N,2]
  const int E = in_sizes[1] / 2;  // edge_index [2,E]
  const int G = out_size / 3;     // logits [G,3]

  const int* src = ei;
  const int* dstp = ei + E;

  const int B = (N + BSZ - 1) / BSZ;  // <=256 for N<=131072

  size_t NP = ((size_t)N + 256) & ~(size_t)255;
  size_t EP = ((size_t)E + 255) & ~(size_t)255;

  float* dis = (float*)d_ws;                   // NP
  int* rp = (int*)d_ws + NP;                   // NP
  unsigned* csr = (unsigned*)(rp + NP);        // EP
  unsigned* part = (unsigned*)(csr + EP);      // 256*CAP regions
  int* ctrl = (int*)(part + (size_t)256 * CAP);
  int* bucketCount = ctrl;                     // 256 (memset 0 with pooled)
  unsigned* pooled = (unsigned*)(ctrl + 256);  // G*128
  int* bucketBase = (int*)(pooled + (size_t)G * 128);  // 256
  float* arena = (float*)(bucketBase + 256);

  unsigned* xsh = (unsigned*)arena;                 // N uints  (fp16 x2)
  uint4* h1h = (uint4*)(arena + (size_t)N);         // N uint4  (fp16 x8)
  __half* h2h = (__half*)(arena + (size_t)5 * N);   // N*32 fp16

  const int BS = 256;
  auto cdiv = [](long long a, long long b) { return (int)((a + b - 1) / b); };

  // ---- CSR build (bucketCount + pooled zeroed in one small memset)
  hipMemsetAsync(ctrl, 0, (256 + (size_t)G * 128) * 4, stream);
  p2_partition_kernel<<<cdiv(E, P2_TILE), 256, 0, stream>>>(src, dstp, bucketCount, part, E);
  scan_kernel<<<1, 256, 0, stream>>>(bucketCount, bucketBase, B);
  p3_build_kernel<<<B, BSZ, 0, stream>>>(part, bucketCount, bucketBase, x, xsh, dis, rp, csr, N, B, E);

  // ---- fused layers
  layer1_kernel<<<cdiv(N, BS), BS, 0, stream>>>(rp, csr, dis, xsh, W1, b1, h1h, N);
  layer2_kernel<<<cdiv(N, BS), BS, 0, stream>>>(rp, csr, dis, h1h, W2, b2, h2h, N);
  layer3_pool_kernel<<<cdiv(N, NB3), 128, 0, stream>>>(rp, csr, dis, h2h, W3, b3, batch, pooled, N);

  // ---- head
  head_kernel<<<G, 128, 0, stream>>>(pooled, Wl, bl, out, G);
}

// Round 16
// 118.274 us; speedup vs baseline: 1.1740x; 1.0061x over previous
//
#include <hip/hip_runtime.h>
#include <hip/hip_fp16.h>

// 3-layer GCN, input-dim aggregation (A(XW) = (AX)W), single-pass bucketed
// CSR build (fixed-capacity regions), fully fused layers, fp16 gather-source
// arrays (fp32 accumulate):
//   xs [N,2] fp16 -- layer1 gather   h1s [N,8] fp16 -- layer2 gather
//   h2s [N,32] fp16 -- layer3 gather
// R16: (a) bucket-base scan fused into p3 (each block scans bucketCount in
// LDS; scan kernel launch removed); (b) layer2 uses 2 threads/node with
// __shfl_xor edge-split + MLP-split (tail-variance halved without R14's
// perm overhead).

#define BSHIFT 9
#define BSZ 512
#define P2_TILE 2048
#define CAP 16384
#define SRCMASK 0x1FFFF
#define NB3 32  // nodes per layer3 block

__device__ __forceinline__ unsigned fenc(float x) {
  unsigned b = __float_as_uint(x);
  return (b & 0x80000000u) ? ~b : (b | 0x80000000u);
}
__device__ __forceinline__ float fdec(unsigned k) {
  return (k & 0x80000000u) ? __uint_as_float(k ^ 0x80000000u)
                           : __uint_as_float(~k);
}
__device__ __forceinline__ unsigned pack2(float a, float b) {
  __half2 h = __floats2half2_rn(a, b);
  return *reinterpret_cast<unsigned*>(&h);
}
__device__ __forceinline__ float2 unpack2(unsigned u) {
  __half2 h = *reinterpret_cast<__half2*>(&u);
  return __half22float2(h);
}

// ---------------- CSR build ----------------

// partition edges into fixed-capacity bucket regions; LDS-reordered so
// global writes are run-coalesced. bucketCount doubles as region cursor.
__global__ __launch_bounds__(256) void p2_partition_kernel(
    const int* __restrict__ src, const int* __restrict__ dst,
    int* __restrict__ bucketCount, unsigned* __restrict__ part, int E) {
  __shared__ int hist[256];
  __shared__ int lbase[256];
  __shared__ int gbase[256];
  __shared__ int cur[256];
  __shared__ unsigned sbuf[P2_TILE];
  __shared__ unsigned abuf[P2_TILE];
  int t = threadIdx.x;
  int e0 = blockIdx.x * P2_TILE;
  int cnt = min(P2_TILE, E - e0);

  hist[t] = 0;
  __syncthreads();

  int myb[P2_TILE / 256];
  unsigned myp[P2_TILE / 256];
#pragma unroll
  for (int k = 0; k < P2_TILE / 256; ++k) {
    int i = t + k * 256;
    if (i < cnt) {
      int e = e0 + i;
      int d = dst[e];
      int b = d >> BSHIFT;
      myb[k] = b;
      myp[k] = ((unsigned)(d & (BSZ - 1)) << 17) | (unsigned)src[e];
      atomicAdd(&hist[b], 1);
    } else {
      myb[k] = -1;
      myp[k] = 0;
    }
  }
  __syncthreads();

  int v = hist[t];
  lbase[t] = v;
  __syncthreads();
  for (int o = 1; o < 256; o <<= 1) {
    int u = (t >= o) ? lbase[t - o] : 0;
    __syncthreads();
    lbase[t] += u;
    __syncthreads();
  }
  int excl = lbase[t] - v;
  __syncthreads();
  lbase[t] = excl;
  if (v > 0) gbase[t] = atomicAdd(&bucketCount[t], v);  // region reservation
  cur[t] = 0;
  __syncthreads();

#pragma unroll
  for (int k = 0; k < P2_TILE / 256; ++k) {
    int b = myb[k];
    if (b >= 0) {
      int pos = atomicAdd(&cur[b], 1);
      int li = lbase[b] + pos;
      sbuf[li] = myp[k];
      abuf[li] = (unsigned)(b * CAP + gbase[b] + pos);
    }
  }
  __syncthreads();

#pragma unroll
  for (int k = 0; k < P2_TILE / 256; ++k) {
    int i = t + k * 256;
    if (i < cnt) part[abuf[i]] = sbuf[i];
  }
}

// per-bucket: scans bucketCount in LDS for its own base (scan kernel fused),
// local deg hist -> dis, rp, fp16-prescaled x; scatter region->compact csr.
__global__ __launch_bounds__(512) void p3_build_kernel(
    const unsigned* __restrict__ part, const int* __restrict__ bucketCount,
    const float* __restrict__ x, unsigned* __restrict__ xsh,
    float* __restrict__ dis, int* __restrict__ rp, unsigned* __restrict__ csr,
    int N, int B, int E) {
  __shared__ int hist[BSZ];
  __shared__ int scn[BSZ];
  __shared__ int sb[256];
  int b = blockIdx.x, t = threadIdx.x;
  const unsigned* reg = part + (size_t)b * CAP;
  int cnt = bucketCount[b];

  // fused bucket-base scan: exclusive prefix of bucketCount[0..b-1]
  if (t < 256) sb[t] = (t < B) ? bucketCount[t] : 0;
  __syncthreads();
  for (int o = 1; o < 256; o <<= 1) {
    int u = (t < 256 && t >= o) ? sb[t - o] : 0;
    __syncthreads();
    if (t < 256) sb[t] += u;
    __syncthreads();
  }
  int wbase = sb[b] - cnt;  // exclusive

  hist[t] = 0;
  __syncthreads();
  for (int i = t; i < cnt; i += BSZ) atomicAdd(&hist[reg[i] >> 17], 1);
  __syncthreads();

  int v = hist[t];
  scn[t] = v;
  __syncthreads();
  for (int o = 1; o < BSZ; o <<= 1) {
    int u = (t >= o) ? scn[t - o] : 0;
    __syncthreads();
    scn[t] += u;
    __syncthreads();
  }
  int excl = scn[t] - v;

  int n = (b << BSHIFT) + t;
  if (n < N) {
    float dn = rsqrtf((float)v + 1.0f);
    dis[n] = dn;
    rp[n] = wbase + excl;
    float2 xn = *reinterpret_cast<const float2*>(x + 2 * (size_t)n);
    xsh[n] = pack2(dn * xn.x, dn * xn.y);  // fp16 pre-scaled x
  }
  if (b == B - 1 && t == 0) rp[N] = E;

  hist[t] = excl;  // reuse as cursor
  __syncthreads();
  for (int i = t; i < cnt; i += BSZ) {
    unsigned p = reg[i];
    int pos = atomicAdd(&hist[p >> 17], 1);
    csr[wbase + pos] = p & SRCMASK;
  }
}

// ---------------- fused layers ----------------

// layer1: thread-per-node; gathers fp16 xs (4B/edge); writes fp16 h1s (16B).
__global__ __launch_bounds__(256) void layer1_kernel(
    const int* __restrict__ rp, const unsigned* __restrict__ csr, const float* __restrict__ dis,
    const unsigned* __restrict__ xsh, const float* __restrict__ W1, const float* __restrict__ b1,
    uint4* __restrict__ h1h, int N) {
  __shared__ float sW[16];
  __shared__ float sb[8];
  int t = threadIdx.x;
  if (t < 16) sW[t] = W1[t];
  if (t < 8) sb[t] = b1[t];
  __syncthreads();
  int n = blockIdx.x * blockDim.x + t;
  if (n >= N) return;
  float2 a = unpack2(xsh[n]);  // self
  int j0 = rp[n], j1 = rp[n + 1];
#pragma unroll 4
  for (int j = j0; j < j1; ++j) {
    const float2 v = unpack2(xsh[csr[j]]);
    a.x += v.x;
    a.y += v.y;
  }
  float dn = dis[n];
  float ax = dn * a.x, ay = dn * a.y;
  uint4 pk;
  unsigned* pw = &pk.x;
#pragma unroll
  for (int fc = 0; fc < 4; ++fc) {
    float e0 = dn * fmaxf(ax * sW[fc * 2 + 0] + ay * sW[8 + fc * 2 + 0] + sb[fc * 2 + 0], 0.f);
    float e1 = dn * fmaxf(ax * sW[fc * 2 + 1] + ay * sW[8 + fc * 2 + 1] + sb[fc * 2 + 1], 0.f);
    pw[fc] = pack2(e0, e1);
  }
  h1h[n] = pk;
}

// layer2: 2 threads/node (even/odd edge split, __shfl_xor combine);
// each lane computes 16 of the 32 outputs and writes its half-row.
__global__ __launch_bounds__(256) void layer2_kernel(
    const int* __restrict__ rp, const unsigned* __restrict__ csr, const float* __restrict__ dis,
    const uint4* __restrict__ h1h, const float* __restrict__ W2, const float* __restrict__ b2,
    __half* __restrict__ h2h, int N) {
  __shared__ float sW[256];  // [8][32]
  __shared__ float sb[32];
  int t = threadIdx.x;
  sW[t] = W2[t];
  if (t < 32) sb[t] = b2[t];
  __syncthreads();
  int tid = blockIdx.x * blockDim.x + t;
  int n = tid >> 1;
  if (n >= N) return;
  int half = tid & 1;
  float acc[8] = {0.f, 0.f, 0.f, 0.f, 0.f, 0.f, 0.f, 0.f};
  if (half == 0) {  // self term once
    uint4 sv = h1h[n];
    float2 f0 = unpack2(sv.x), f1 = unpack2(sv.y), f2 = unpack2(sv.z), f3 = unpack2(sv.w);
    acc[0] = f0.x; acc[1] = f0.y; acc[2] = f1.x; acc[3] = f1.y;
    acc[4] = f2.x; acc[5] = f2.y; acc[6] = f3.x; acc[7] = f3.y;
  }
  int j0 = rp[n], j1 = rp[n + 1];
#pragma unroll 4
  for (int j = j0 + half; j < j1; j += 2) {
    uint4 v = h1h[csr[j]];
    float2 g0 = unpack2(v.x), g1 = unpack2(v.y), g2 = unpack2(v.z), g3 = unpack2(v.w);
    acc[0] += g0.x; acc[1] += g0.y; acc[2] += g1.x; acc[3] += g1.y;
    acc[4] += g2.x; acc[5] += g2.y; acc[6] += g3.x; acc[7] += g3.y;
  }
  // combine the pair (lanes tid, tid^1 are adjacent in the wave)
#pragma unroll
  for (int k = 0; k < 8; ++k) acc[k] += __shfl_xor(acc[k], 1);
  float dn = dis[n];
#pragma unroll
  for (int k = 0; k < 8; ++k) acc[k] *= dn;
  // each half computes output features [half*16, half*16+16)
  uint4 pk[2];
  unsigned* pw = &pk[0].x;
#pragma unroll
  for (int fc2 = 0; fc2 < 4; ++fc2) {
    int fc = half * 4 + fc2;
    float4 o;
    o.x = sb[fc * 4 + 0]; o.y = sb[fc * 4 + 1]; o.z = sb[fc * 4 + 2]; o.w = sb[fc * 4 + 3];
#pragma unroll
    for (int k = 0; k < 8; ++k) {
      const float4 w = *reinterpret_cast<const float4*>(&sW[k * 32 + fc * 4]);
      float a = acc[k];
      o.x += a * w.x; o.y += a * w.y; o.z += a * w.z; o.w += a * w.w;
    }
    o.x = dn * fmaxf(o.x, 0.f);
    o.y = dn * fmaxf(o.y, 0.f);
    o.z = dn * fmaxf(o.z, 0.f);
    o.w = dn * fmaxf(o.w, 0.f);
    pw[fc2 * 2 + 0] = pack2(o.x, o.y);
    pw[fc2 * 2 + 1] = pack2(o.z, o.w);
  }
  uint4* dst16 = reinterpret_cast<uint4*>(h2h + (size_t)n * 32);
  dst16[half * 2 + 0] = pk[0];
  dst16[half * 2 + 1] = pk[1];
}

// layer3 fused: 32 nodes per 128-thread block, 4 threads/node, per-node
// register accumulation over fp16 h2s, then matvec + segmented max-pool.
__global__ __launch_bounds__(128) void layer3_pool_kernel(
    const int* __restrict__ rp, const unsigned* __restrict__ csr, const float* __restrict__ dis,
    const __half* __restrict__ h2h, const float* __restrict__ W3, const float* __restrict__ b3,
    const int* __restrict__ batch, unsigned* __restrict__ pooled, int N) {
  __shared__ float rows[NB3][32];
  __shared__ float dnv[NB3];
  int t = threadIdx.x;
  int gi = t >> 2;          // node slot 0..31
  int q = t & 3;            // feature quarter (8 features)

  int n0 = blockIdx.x * NB3;
  int m = min(NB3, N - n0);

  if (t < m) dnv[t] = dis[n0 + t];

  if (gi < m) {
    int n = n0 + gi;
    uint4 sv = *reinterpret_cast<const uint4*>(h2h + (size_t)n * 32 + q * 8);
    float2 f0 = unpack2(sv.x), f1 = unpack2(sv.y), f2 = unpack2(sv.z), f3 = unpack2(sv.w);
    float acc[8] = {f0.x, f0.y, f1.x, f1.y, f2.x, f2.y, f3.x, f3.y};
    int j0 = rp[n], j1 = rp[n + 1];
#pragma unroll 4
    for (int j = j0; j < j1; ++j) {
      int s = csr[j];
      uint4 v = *reinterpret_cast<const uint4*>(h2h + (size_t)s * 32 + q * 8);
      float2 g0 = unpack2(v.x), g1 = unpack2(v.y), g2 = unpack2(v.z), g3 = unpack2(v.w);
      acc[0] += g0.x; acc[1] += g0.y; acc[2] += g1.x; acc[3] += g1.y;
      acc[4] += g2.x; acc[5] += g2.y; acc[6] += g3.x; acc[7] += g3.y;
    }
#pragma unroll
    for (int i = 0; i < 8; ++i) rows[gi][q * 8 + i] = acc[i];
  }
  __syncthreads();

  // matvec + segmented max: thread t owns output feature t (128 threads)
  float Wreg[32];
#pragma unroll
  for (int k = 0; k < 32; ++k) Wreg[k] = W3[k * 128 + t];
  float bb = b3[t];

  int curg = batch[n0];
  float runmax = -INFINITY;
  for (int r = 0; r < m; ++r) {
    int g = batch[n0 + r];
    if (g != curg) {
      atomicMax(&pooled[(size_t)curg * 128 + t], fenc(runmax));
      runmax = -INFINITY;
      curg = g;
    }
    float acc = 0.f;
#pragma unroll
    for (int k = 0; k < 32; ++k) acc += rows[r][k] * Wreg[k];
    runmax = fmaxf(runmax, dnv[r] * acc + bb);
  }
  atomicMax(&pooled[(size_t)curg * 128 + t], fenc(runmax));
}

__global__ __launch_bounds__(128) void head_kernel(
    const unsigned* __restrict__ pooled, const float* __restrict__ Wl,
    const float* __restrict__ bl, float* __restrict__ out, int G) {
  int g = blockIdx.x;
  int t = threadIdx.x;  // 128
  float p = fdec(pooled[(size_t)g * 128 + t]);
  __shared__ float red[128];
  __shared__ float sj[3];
  for (int j = 0; j < 3; ++j) {
    red[t] = p * Wl[t * 3 + j];
    __syncthreads();
    for (int k = 64; k > 0; k >>= 1) {
      if (t < k) red[t] += red[t + k];
      __syncthreads();
    }
    if (t == 0) sj[j] = red[0];
    __syncthreads();
  }
  if (t == 0) {
    float l0 = sj[0] + bl[0], l1 = sj[1] + bl[1], l2 = sj[2] + bl[2];
    float m = fmaxf(l0, fmaxf(l1, l2));
    float lse = logf(expf(l0 - m) + expf(l1 - m) + expf(l2 - m));
    out[g * 3 + 0] = l0 - m - lse;
    out[g * 3 + 1] = l1 - m - lse;
    out[g * 3 + 2] = l2 - m - lse;
  }
}

extern "C" void kernel_launch(void* const* d_in, const int* in_sizes, int n_in,
                              void* d_out, int out_size, void* d_ws, size_t ws_size,
                              hipStream_t stream) {
  const float* x = (const float*)d_in[0];
  const int* ei = (const int*)d_in[1];
  const int* batch = (const int*)d_in[2];
  const float* W1 = (const float*)d_in[3];
  const float* b1 = (const float*)d_in[4];
  const float* W2 = (const float*)d_in[5];
  const float* b2 = (const float*)d_in[6];
  const float* W3 = (const float*)d_in[7];
  const float* b3 = (const float*)d_in[8];
  const float* Wl = (const float*)d_in[9];
  const float* bl = (const float*)d_in[10];
  float* out = (float*)d_out;

  const int N = in_sizes[0] / 2;  // x [N,2]
  const int E = in_sizes[1] / 2;  // edge_index [2,E]
  const int G = out_size / 3;     // logits [G,3]

  const int* src = ei;
  const int* dstp = ei + E;

  const int B = (N + BSZ - 1) / BSZ;  // <=256 for N<=131072

  size_t NP = ((size_t)N + 256) & ~(size_t)255;
  size_t EP = ((size_t)E + 255) & ~(size_t)255;

  float* dis = (float*)d_ws;                   // NP
  int* rp = (int*)d_ws + NP;                   // NP
  unsigned* csr = (unsigned*)(rp + NP);        // EP
  unsigned* part = (unsigned*)(csr + EP);      // 256*CAP regions
  int* ctrl = (int*)(part + (size_t)256 * CAP);
  int* bucketCount = ctrl;                     // 256 (memset 0 with pooled)
  unsigned* pooled = (unsigned*)(ctrl + 256);  // G*128
  float* arena = (float*)(pooled + (size_t)G * 128);

  unsigned* xsh = (unsigned*)arena;                 // N uints  (fp16 x2)
  uint4* h1h = (uint4*)(arena + (size_t)N);         // N uint4  (fp16 x8)
  __half* h2h = (__half*)(arena + (size_t)5 * N);   // N*32 fp16

  const int BS = 256;
  auto cdiv = [](long long a, long long b) { return (int)((a + b - 1) / b); };

  // ---- CSR build (bucketCount + pooled zeroed in one small memset)
  hipMemsetAsync(ctrl, 0, (256 + (size_t)G * 128) * 4, stream);
  p2_partition_kernel<<<cdiv(E, P2_TILE), 256, 0, stream>>>(src, dstp, bucketCount, part, E);
  p3_build_kernel<<<B, BSZ, 0, stream>>>(part, bucketCount, x, xsh, dis, rp, csr, N, B, E);

  // ---- fused layers
  layer1_kernel<<<cdiv(N, BS), BS, 0, stream>>>(rp, csr, dis, xsh, W1, b1, h1h, N);
  layer2_kernel<<<cdiv((long long)N * 2, BS), BS, 0, stream>>>(rp, csr, dis, h1h, W2, b2, h2h, N);
  layer3_pool_kernel<<<cdiv(N, NB3), 128, 0, stream>>>(rp, csr, dis, h2h, W3, b3, batch, pooled, N);

  // ---- head
  head_kernel<<<G, 128, 0, stream>>>(pooled, Wl, bl, out, G);
}